// Round 6
// baseline (338.062 us; speedup 1.0000x reference)
//
#include <hip/hip_runtime.h>
#include <math.h>

#define N_REF   50000
#define BATCH   16
#define KDIM    4096          // 32*128
#define CHUNK   256           // k-chunk in floats
#define NCHUNK  (KDIM / CHUNK) // 16
#define RPB     16            // n-rows per block
#define RPW     4             // n-rows per wave (unique rows -> raw read exactly once)

typedef float f32x4 __attribute__((ext_vector_type(4)));  // native vec for nontemporal builtin

// K1: dist'[b,n] = r2[n] - 2*dot(x[b], raw[n])   (x2[b] dropped: softmax-invariant)
//
// Barrier-free: the old LDS staging of x did no cross-lane redistribution
// (lane reads exactly the slice it loaded), so x is loaded straight from
// global — it's 256 KB, re-read by all blocks, L1/L2-hot. raw loads are
// nontemporal (read-once) to keep x resident in the caches.
// No min-waves launch bound: R1's (256,3) capped VGPR at 84 -> 1 GB scratch spill.
__global__ __launch_bounds__(256) void dist_kernel(const float* __restrict__ x,
                                                   const float* __restrict__ raw,
                                                   float* __restrict__ dist)
{
    const int tid  = threadIdx.x;
    const int lane = tid & 63;
    const int wv   = tid >> 6;               // 0..3
    const long n_base = (long)blockIdx.x * RPB + (long)wv * RPW;

    float acc[BATCH][RPW];
    #pragma unroll
    for (int b = 0; b < BATCH; ++b)
        #pragma unroll
        for (int r = 0; r < RPW; ++r) acc[b][r] = 0.f;
    float r2a[RPW] = {0.f, 0.f, 0.f, 0.f};

    const float* xl = x + lane * 4;          // lane's private x slice base

    #pragma unroll 1
    for (int c = 0; c < NCHUNK; ++c) {
        // HBM stream: 4 rows x float4, coalesced, nontemporal (read-once)
        f32x4 rv[RPW];
        #pragma unroll
        for (int r = 0; r < RPW; ++r) {
            rv[r] = __builtin_nontemporal_load(
                (const f32x4*)(raw + (size_t)(n_base + r) * KDIM
                                   + (size_t)c * CHUNK + lane * 4));
            r2a[r] = fmaf(rv[r].x, rv[r].x, r2a[r]);
            r2a[r] = fmaf(rv[r].y, rv[r].y, r2a[r]);
            r2a[r] = fmaf(rv[r].z, rv[r].z, r2a[r]);
            r2a[r] = fmaf(rv[r].w, rv[r].w, r2a[r]);
        }
        // x fragments: L1/L2-hit; lane-private, no LDS round-trip needed
        #pragma unroll
        for (int b = 0; b < BATCH; ++b) {
            const f32x4 xv = *(const f32x4*)(xl + (size_t)b * KDIM + (size_t)c * CHUNK);
            #pragma unroll
            for (int r = 0; r < RPW; ++r) {
                acc[b][r] = fmaf(rv[r].x, xv.x, acc[b][r]);
                acc[b][r] = fmaf(rv[r].y, xv.y, acc[b][r]);
                acc[b][r] = fmaf(rv[r].z, xv.z, acc[b][r]);
                acc[b][r] = fmaf(rv[r].w, xv.w, acc[b][r]);
            }
        }
    }

    // Cross-lane reduce of 64 accumulators: value v = b*4+r ends (summed) on lane v.
    float vals[64];
    #pragma unroll
    for (int b = 0; b < BATCH; ++b)
        #pragma unroll
        for (int r = 0; r < RPW; ++r) vals[b * RPW + r] = acc[b][r];

    #pragma unroll
    for (int k = 0; k < 6; ++k) {
        const int bit = 1 << k;
        const bool hi = (lane & bit) != 0;
        #pragma unroll
        for (int i = 0; i < (64 >> (k + 1)); ++i) {
            const float a  = vals[2 * i];
            const float bb = vals[2 * i + 1];
            const float keep = hi ? bb : a;
            const float send = hi ? a  : bb;
            const float recv = __shfl_xor(send, bit, 64);
            vals[i] = keep + recv;
        }
    }

    // r2: broadcast-reduce the 4 row sums to all lanes
    #pragma unroll
    for (int r = 0; r < RPW; ++r) {
        #pragma unroll
        for (int k = 0; k < 6; ++k)
            r2a[r] += __shfl_xor(r2a[r], 1 << k, 64);
    }

    const int b_out = lane >> 2;
    const int r_out = lane & 3;
    const float r2v = (r_out == 0) ? r2a[0] : (r_out == 1) ? r2a[1]
                    : (r_out == 2) ? r2a[2] : r2a[3];
    dist[(size_t)b_out * N_REF + (size_t)(n_base + r_out)] = r2v - 2.0f * vals[0];
}

// ---------------- softmax: two-stage, full-device ----------------
#define SMB   25      // col-blocks per row
#define SMC   2000    // cols per block (= 500 float4)

__global__ __launch_bounds__(256) void softmax_part(const float* __restrict__ d,
                                                    float2* __restrict__ part)
{
    const int row = blockIdx.y, cb = blockIdx.x;
    const float* p = d + (size_t)row * N_REF + (size_t)cb * SMC;
    const int tid = threadIdx.x;

    float m = -INFINITY, s = 0.f;
    #pragma unroll
    for (int i = 0; i < 2; ++i) {
        const int q = tid + i * 256;          // float4 index within block
        if (q < SMC / 4) {
            const float4 v = *(const float4*)(p + q * 4);
            const float M = fmaxf(m, fmaxf(fmaxf(v.x, v.y), fmaxf(v.z, v.w)));
            s = s * __expf(m - M) + __expf(v.x - M) + __expf(v.y - M)
                                  + __expf(v.z - M) + __expf(v.w - M);
            m = M;
        }
    }
    #pragma unroll
    for (int k = 1; k < 64; k <<= 1) {
        const float mo = __shfl_xor(m, k, 64);
        const float so = __shfl_xor(s, k, 64);
        const float M  = fmaxf(m, mo);
        s = s * __expf(m - M) + so * __expf(mo - M);
        m = M;
    }
    __shared__ float2 wsum[4];
    const int wv = tid >> 6, lane = tid & 63;
    if (lane == 0) wsum[wv] = make_float2(m, s);
    __syncthreads();
    if (tid == 0) {
        float M = wsum[0].x, S = wsum[0].y;
        #pragma unroll
        for (int i = 1; i < 4; ++i) {
            const float M2 = fmaxf(M, wsum[i].x);
            S = S * __expf(M - M2) + wsum[i].y * __expf(wsum[i].x - M2);
            M = M2;
        }
        part[row * SMB + cb] = make_float2(M, S);
    }
}

__global__ __launch_bounds__(256) void softmax_norm(float* __restrict__ d,
                                                    const float2* __restrict__ part)
{
    const int row = blockIdx.y, cb = blockIdx.x;
    const int tid = threadIdx.x;

    // every block redundantly reduces the 25 row-partials (tiny, L2-hit)
    float M = -INFINITY, S = 0.f;
    #pragma unroll
    for (int i = 0; i < SMB; ++i) {
        const float2 ps = part[row * SMB + i];
        const float M2 = fmaxf(M, ps.x);
        S = S * __expf(M - M2) + ps.y * __expf(ps.x - M2);
        M = M2;
    }
    const float Sinv = 1.f / S;

    float* p = d + (size_t)row * N_REF + (size_t)cb * SMC;
    #pragma unroll
    for (int i = 0; i < 2; ++i) {
        const int q = tid + i * 256;
        if (q < SMC / 4) {
            float4 v = *(float4*)(p + q * 4);
            v.x = __expf(v.x - M) * Sinv;
            v.y = __expf(v.y - M) * Sinv;
            v.z = __expf(v.z - M) * Sinv;
            v.w = __expf(v.w - M) * Sinv;
            *(float4*)(p + q * 4) = v;
        }
    }
}

extern "C" void kernel_launch(void* const* d_in, const int* in_sizes, int n_in,
                              void* d_out, int out_size, void* d_ws, size_t ws_size,
                              hipStream_t stream) {
    const float* x   = (const float*)d_in[0];   // [16][32][128]
    const float* raw = (const float*)d_in[1];   // [50000][32][128]
    float* out = (float*)d_out;                 // [16][50000]
    float2* part = (float2*)d_ws;               // 16*25 float2 partials

    dist_kernel<<<N_REF / RPB, 256, 0, stream>>>(x, raw, out);
    softmax_part<<<dim3(SMB, BATCH), 256, 0, stream>>>(out, part);
    softmax_norm<<<dim3(SMB, BATCH), 256, 0, stream>>>(out, part);
}

// Round 7
// 197.141 us; speedup vs baseline: 1.7148x; 1.7148x over previous
//
#include <hip/hip_runtime.h>
#include <math.h>

#define N_REF   50000
#define BATCH   16
#define KDIM    4096          // 32*128
#define CHUNK   256           // k-chunk in floats
#define NCHUNK  (KDIM / CHUNK) // 16
#define RPB     16            // n-rows per block
#define RPW     4             // n-rows per wave (unique rows -> raw read exactly once)

typedef __attribute__((address_space(3))) uint32_t lds_u32;
typedef const __attribute__((address_space(1))) uint32_t glb_u32;

// K1: dist'[b,n] = r2[n] - 2*dot(x[b], raw[n])   (x2[b] dropped: softmax-invariant)
//
// R3 structure (LDS-staged x, validated 191us; R5's no-LDS variant regressed to
// 338us — x through VMEM thrashes L1) + T4 counted-vmcnt barrier:
// per phase, issue STAGE (oldest) then next-chunk rv prefetch (newest), compute,
// then `s_waitcnt vmcnt(4)` + raw s_barrier — drains the 4 stage loads (LDS
// visibility) while the 4 rv prefetch loads stay in flight ACROSS the barrier.
// __syncthreads would emit vmcnt(0) and kill the prefetch (m97 structural stall).
__global__ __launch_bounds__(256) void dist_kernel(const float* __restrict__ x,
                                                   const float* __restrict__ raw,
                                                   float* __restrict__ dist)
{
    __shared__ float xs[2][BATCH * CHUNK];   // double-buffered, 2 x 16 KiB
    const int tid  = threadIdx.x;
    const int lane = tid & 63;
    const int wv   = tid >> 6;               // 0..3
    const long n_base = (long)blockIdx.x * RPB + (long)wv * RPW;

    float acc[BATCH][RPW];
    #pragma unroll
    for (int b = 0; b < BATCH; ++b)
        #pragma unroll
        for (int r = 0; r < RPW; ++r) acc[b][r] = 0.f;
    float r2a[RPW] = {0.f, 0.f, 0.f, 0.f};
    float4 rvA[RPW], rvB[RPW];

#define STAGE(buf, c) do {                                                      \
        _Pragma("unroll")                                                       \
        for (int i_ = 0; i_ < 4; ++i_) {                                        \
            const int b_ = i_ * 4 + wv;                                         \
            const float* g_ = x + (size_t)b_ * KDIM + (size_t)(c) * CHUNK + lane * 4; \
            const float* l_ = &xs[buf][b_ * CHUNK];                             \
            __builtin_amdgcn_global_load_lds((glb_u32*)g_, (lds_u32*)l_, 16, 0, 0); \
        }                                                                       \
    } while (0)

#define LOADRV(dst, c) do {                                                     \
        _Pragma("unroll")                                                       \
        for (int r_ = 0; r_ < RPW; ++r_)                                        \
            dst[r_] = *(const float4*)(raw + (size_t)(n_base + r_) * KDIM       \
                                           + (size_t)(c) * CHUNK + lane * 4);   \
    } while (0)

#define COMPUTE(rv, buf) do {                                                   \
        _Pragma("unroll")                                                       \
        for (int b_ = 0; b_ < BATCH; ++b_) {                                    \
            const float4 xv_ = *(const float4*)(&xs[buf][b_ * CHUNK + lane * 4]); \
            _Pragma("unroll")                                                   \
            for (int r_ = 0; r_ < RPW; ++r_) {                                  \
                acc[b_][r_] = fmaf(rv[r_].x, xv_.x, acc[b_][r_]);               \
                acc[b_][r_] = fmaf(rv[r_].y, xv_.y, acc[b_][r_]);               \
                acc[b_][r_] = fmaf(rv[r_].z, xv_.z, acc[b_][r_]);               \
                acc[b_][r_] = fmaf(rv[r_].w, xv_.w, acc[b_][r_]);               \
            }                                                                   \
        }                                                                       \
        _Pragma("unroll")                                                       \
        for (int r_ = 0; r_ < RPW; ++r_) {                                      \
            r2a[r_] = fmaf(rv[r_].x, rv[r_].x, r2a[r_]);                        \
            r2a[r_] = fmaf(rv[r_].y, rv[r_].y, r2a[r_]);                        \
            r2a[r_] = fmaf(rv[r_].z, rv[r_].z, r2a[r_]);                        \
            r2a[r_] = fmaf(rv[r_].w, rv[r_].w, r2a[r_]);                        \
        }                                                                       \
    } while (0)

    // counted-vmcnt barrier: drains the 4 stage loads (issued oldest in the
    // phase), leaves the 4 rv prefetch loads (newest) in flight. "memory"
    // clobber + sched_barrier(0) fence IR/scheduler motion of the next phase's
    // STAGE (which overwrites the buffer other waves are still reading).
#define PHASE_BARRIER() do {                                                    \
        asm volatile("s_waitcnt vmcnt(4)" ::: "memory");                        \
        __builtin_amdgcn_s_barrier();                                           \
        __builtin_amdgcn_sched_barrier(0);                                      \
    } while (0)

    // prologue: stage chunk 0, prefetch rv chunk 0
    STAGE(0, 0);
    LOADRV(rvA, 0);
    PHASE_BARRIER();

    // steady state, 2 chunks per iteration (static rvA/rvB names)
    #pragma unroll 1
    for (int cc = 0; cc < NCHUNK / 2 - 1; ++cc) {
        STAGE(1, 2 * cc + 1);       // oldest in phase
        LOADRV(rvB, 2 * cc + 1);    // newest: survives the barrier
        COMPUTE(rvA, 0);            // compiler waits rvA via vmcnt(8)
        PHASE_BARRIER();
        STAGE(0, 2 * cc + 2);
        LOADRV(rvA, 2 * cc + 2);
        COMPUTE(rvB, 1);
        PHASE_BARRIER();
    }
    // tail: chunks 14 (in buf0/rvA), 15
    STAGE(1, NCHUNK - 1);
    LOADRV(rvB, NCHUNK - 1);
    COMPUTE(rvA, 0);
    PHASE_BARRIER();
    COMPUTE(rvB, 1);

    // Cross-lane reduce of 64 accumulators: value v = b*4+r ends (summed) on lane v.
    float vals[64];
    #pragma unroll
    for (int b = 0; b < BATCH; ++b)
        #pragma unroll
        for (int r = 0; r < RPW; ++r) vals[b * RPW + r] = acc[b][r];

    #pragma unroll
    for (int k = 0; k < 6; ++k) {
        const int bit = 1 << k;
        const bool hi = (lane & bit) != 0;
        #pragma unroll
        for (int i = 0; i < (64 >> (k + 1)); ++i) {
            const float a  = vals[2 * i];
            const float bb = vals[2 * i + 1];
            const float keep = hi ? bb : a;
            const float send = hi ? a  : bb;
            const float recv = __shfl_xor(send, bit, 64);
            vals[i] = keep + recv;
        }
    }

    // r2: broadcast-reduce the 4 row sums to all lanes
    #pragma unroll
    for (int r = 0; r < RPW; ++r) {
        #pragma unroll
        for (int k = 0; k < 6; ++k)
            r2a[r] += __shfl_xor(r2a[r], 1 << k, 64);
    }

    const int b_out = lane >> 2;
    const int r_out = lane & 3;
    const float r2v = (r_out == 0) ? r2a[0] : (r_out == 1) ? r2a[1]
                    : (r_out == 2) ? r2a[2] : r2a[3];
    dist[(size_t)b_out * N_REF + (size_t)(n_base + r_out)] = r2v - 2.0f * vals[0];
}

// ---------------- softmax: two-stage, full-device ----------------
#define SMB   25      // col-blocks per row
#define SMC   2000    // cols per block (= 500 float4)

__global__ __launch_bounds__(256) void softmax_part(const float* __restrict__ d,
                                                    float2* __restrict__ part)
{
    const int row = blockIdx.y, cb = blockIdx.x;
    const float* p = d + (size_t)row * N_REF + (size_t)cb * SMC;
    const int tid = threadIdx.x;

    float m = -INFINITY, s = 0.f;
    #pragma unroll
    for (int i = 0; i < 2; ++i) {
        const int q = tid + i * 256;          // float4 index within block
        if (q < SMC / 4) {
            const float4 v = *(const float4*)(p + q * 4);
            const float M = fmaxf(m, fmaxf(fmaxf(v.x, v.y), fmaxf(v.z, v.w)));
            s = s * __expf(m - M) + __expf(v.x - M) + __expf(v.y - M)
                                  + __expf(v.z - M) + __expf(v.w - M);
            m = M;
        }
    }
    #pragma unroll
    for (int k = 1; k < 64; k <<= 1) {
        const float mo = __shfl_xor(m, k, 64);
        const float so = __shfl_xor(s, k, 64);
        const float M  = fmaxf(m, mo);
        s = s * __expf(m - M) + so * __expf(mo - M);
        m = M;
    }
    __shared__ float2 wsum[4];
    const int wv = tid >> 6, lane = tid & 63;
    if (lane == 0) wsum[wv] = make_float2(m, s);
    __syncthreads();
    if (tid == 0) {
        float M = wsum[0].x, S = wsum[0].y;
        #pragma unroll
        for (int i = 1; i < 4; ++i) {
            const float M2 = fmaxf(M, wsum[i].x);
            S = S * __expf(M - M2) + wsum[i].y * __expf(wsum[i].x - M2);
            M = M2;
        }
        part[row * SMB + cb] = make_float2(M, S);
    }
}

__global__ __launch_bounds__(256) void softmax_norm(float* __restrict__ d,
                                                    const float2* __restrict__ part)
{
    const int row = blockIdx.y, cb = blockIdx.x;
    const int tid = threadIdx.x;

    // every block redundantly reduces the 25 row-partials (tiny, L2-hit)
    float M = -INFINITY, S = 0.f;
    #pragma unroll
    for (int i = 0; i < SMB; ++i) {
        const float2 ps = part[row * SMB + i];
        const float M2 = fmaxf(M, ps.x);
        S = S * __expf(M - M2) + ps.y * __expf(ps.x - M2);
        M = M2;
    }
    const float Sinv = 1.f / S;

    float* p = d + (size_t)row * N_REF + (size_t)cb * SMC;
    #pragma unroll
    for (int i = 0; i < 2; ++i) {
        const int q = tid + i * 256;
        if (q < SMC / 4) {
            float4 v = *(float4*)(p + q * 4);
            v.x = __expf(v.x - M) * Sinv;
            v.y = __expf(v.y - M) * Sinv;
            v.z = __expf(v.z - M) * Sinv;
            v.w = __expf(v.w - M) * Sinv;
            *(float4*)(p + q * 4) = v;
        }
    }
}

extern "C" void kernel_launch(void* const* d_in, const int* in_sizes, int n_in,
                              void* d_out, int out_size, void* d_ws, size_t ws_size,
                              hipStream_t stream) {
    const float* x   = (const float*)d_in[0];   // [16][32][128]
    const float* raw = (const float*)d_in[1];   // [50000][32][128]
    float* out = (float*)d_out;                 // [16][50000]
    float2* part = (float2*)d_ws;               // 16*25 float2 partials

    dist_kernel<<<N_REF / RPB, 256, 0, stream>>>(x, raw, out);
    softmax_part<<<dim3(SMB, BATCH), 256, 0, stream>>>(out, part);
    softmax_norm<<<dim3(SMB, BATCH), 256, 0, stream>>>(out, part);
}

// Round 8
// 183.489 us; speedup vs baseline: 1.8424x; 1.0744x over previous
//
#include <hip/hip_runtime.h>
#include <math.h>

#define N_REF   50000
#define BATCH   16
#define KDIM    4096          // 32*128
#define CHUNK   256           // k-chunk in floats
#define NCHUNK  (KDIM / CHUNK) // 16
#define RPB     16            // n-rows per block
#define RPW     4             // n-rows per wave (unique rows -> raw read exactly once)

typedef float f32x4 __attribute__((ext_vector_type(4)));  // native vec for nontemporal builtin
typedef __attribute__((address_space(3))) uint32_t lds_u32;
typedef const __attribute__((address_space(1))) uint32_t glb_u32;

// K1: dist'[b,n] = r2[n] - 2*dot(x[b], raw[n])   (x2[b] dropped: softmax-invariant)
//
// R3 structure (191us validated): LDS-staged x via global_load_lds, double
// buffer, one __syncthreads per chunk. NEW: raw loads are NONTEMPORAL —
// the 819 MB raw stream was evicting x's 256 KB from the per-XCD L2, turning
// the 800 MB device-wide x re-read into partial HBM misses (~250 MB extra
// fetch; 175us x 6.3TB/s ~= 1.1 GB observed-equivalent). Evict-first raw
// keeps x L2-resident; FETCH should drop to ~840 MB.
// R6's counted-vmcnt barrier was neutral (197 vs 191) -> reverted.
// No min-waves launch bound: R1's (256,3) capped VGPR at 84 -> 1 GB spill.
__global__ __launch_bounds__(256) void dist_kernel(const float* __restrict__ x,
                                                   const float* __restrict__ raw,
                                                   float* __restrict__ dist)
{
    __shared__ float xs[2][BATCH * CHUNK];   // double-buffered, 2 x 16 KiB
    const int tid  = threadIdx.x;
    const int lane = tid & 63;
    const int wv   = tid >> 6;               // 0..3
    const long n_base = (long)blockIdx.x * RPB + (long)wv * RPW;

    float acc[BATCH][RPW];
    #pragma unroll
    for (int b = 0; b < BATCH; ++b)
        #pragma unroll
        for (int r = 0; r < RPW; ++r) acc[b][r] = 0.f;
    float r2a[RPW] = {0.f, 0.f, 0.f, 0.f};
    f32x4 rv[RPW];

#define STAGE(buf, c) do {                                                      \
        _Pragma("unroll")                                                       \
        for (int i_ = 0; i_ < 4; ++i_) {                                        \
            const int b_ = i_ * 4 + wv;                                         \
            const float* g_ = x + (size_t)b_ * KDIM + (size_t)(c) * CHUNK + lane * 4; \
            const float* l_ = &xs[buf][b_ * CHUNK];                             \
            __builtin_amdgcn_global_load_lds((glb_u32*)g_, (lds_u32*)l_, 16, 0, 0); \
        }                                                                       \
    } while (0)

    // nontemporal: raw is read-once; evict-first policy preserves x in L2
#define LOADRV(c) do {                                                          \
        _Pragma("unroll")                                                       \
        for (int r_ = 0; r_ < RPW; ++r_)                                        \
            rv[r_] = __builtin_nontemporal_load(                                \
                (const f32x4*)(raw + (size_t)(n_base + r_) * KDIM               \
                                   + (size_t)(c) * CHUNK + lane * 4));          \
    } while (0)

#define COMPUTE(buf) do {                                                       \
        _Pragma("unroll")                                                       \
        for (int r_ = 0; r_ < RPW; ++r_) {                                      \
            r2a[r_] = fmaf(rv[r_].x, rv[r_].x, r2a[r_]);                        \
            r2a[r_] = fmaf(rv[r_].y, rv[r_].y, r2a[r_]);                        \
            r2a[r_] = fmaf(rv[r_].z, rv[r_].z, r2a[r_]);                        \
            r2a[r_] = fmaf(rv[r_].w, rv[r_].w, r2a[r_]);                        \
        }                                                                       \
        _Pragma("unroll")                                                       \
        for (int b_ = 0; b_ < BATCH; ++b_) {                                    \
            const f32x4 xv_ = *(const f32x4*)(&xs[buf][b_ * CHUNK + lane * 4]); \
            _Pragma("unroll")                                                   \
            for (int r_ = 0; r_ < RPW; ++r_) {                                  \
                acc[b_][r_] = fmaf(rv[r_].x, xv_.x, acc[b_][r_]);               \
                acc[b_][r_] = fmaf(rv[r_].y, xv_.y, acc[b_][r_]);               \
                acc[b_][r_] = fmaf(rv[r_].z, xv_.z, acc[b_][r_]);               \
                acc[b_][r_] = fmaf(rv[r_].w, xv_.w, acc[b_][r_]);               \
            }                                                                   \
        }                                                                       \
    } while (0)

    // prologue: stage chunk 0, barrier (drains vmcnt -> buffer 0 ready)
    STAGE(0, 0);
    __syncthreads();

    int buf = 0;
    #pragma unroll 1
    for (int c = 0; c < NCHUNK - 1; ++c) {
        LOADRV(c);              // oldest: pre-FMA wait leaves stage in flight
        STAGE(buf ^ 1, c + 1);
        COMPUTE(buf);
        __syncthreads();
        buf ^= 1;
    }
    LOADRV(NCHUNK - 1);
    COMPUTE(buf);

    // Cross-lane reduce of 64 accumulators: value v = b*4+r ends (summed) on lane v.
    float vals[64];
    #pragma unroll
    for (int b = 0; b < BATCH; ++b)
        #pragma unroll
        for (int r = 0; r < RPW; ++r) vals[b * RPW + r] = acc[b][r];

    #pragma unroll
    for (int k = 0; k < 6; ++k) {
        const int bit = 1 << k;
        const bool hi = (lane & bit) != 0;
        #pragma unroll
        for (int i = 0; i < (64 >> (k + 1)); ++i) {
            const float a  = vals[2 * i];
            const float bb = vals[2 * i + 1];
            const float keep = hi ? bb : a;
            const float send = hi ? a  : bb;
            const float recv = __shfl_xor(send, bit, 64);
            vals[i] = keep + recv;
        }
    }

    // r2: broadcast-reduce the 4 row sums to all lanes
    #pragma unroll
    for (int r = 0; r < RPW; ++r) {
        #pragma unroll
        for (int k = 0; k < 6; ++k)
            r2a[r] += __shfl_xor(r2a[r], 1 << k, 64);
    }

    const int b_out = lane >> 2;
    const int r_out = lane & 3;
    const float r2v = (r_out == 0) ? r2a[0] : (r_out == 1) ? r2a[1]
                    : (r_out == 2) ? r2a[2] : r2a[3];
    dist[(size_t)b_out * N_REF + (size_t)(n_base + r_out)] = r2v - 2.0f * vals[0];
}

// ---------------- softmax: two-stage, full-device ----------------
#define SMB   25      // col-blocks per row
#define SMC   2000    // cols per block (= 500 float4)

__global__ __launch_bounds__(256) void softmax_part(const float* __restrict__ d,
                                                    float2* __restrict__ part)
{
    const int row = blockIdx.y, cb = blockIdx.x;
    const float* p = d + (size_t)row * N_REF + (size_t)cb * SMC;
    const int tid = threadIdx.x;

    float m = -INFINITY, s = 0.f;
    #pragma unroll
    for (int i = 0; i < 2; ++i) {
        const int q = tid + i * 256;          // float4 index within block
        if (q < SMC / 4) {
            const float4 v = *(const float4*)(p + q * 4);
            const float M = fmaxf(m, fmaxf(fmaxf(v.x, v.y), fmaxf(v.z, v.w)));
            s = s * __expf(m - M) + __expf(v.x - M) + __expf(v.y - M)
                                  + __expf(v.z - M) + __expf(v.w - M);
            m = M;
        }
    }
    #pragma unroll
    for (int k = 1; k < 64; k <<= 1) {
        const float mo = __shfl_xor(m, k, 64);
        const float so = __shfl_xor(s, k, 64);
        const float M  = fmaxf(m, mo);
        s = s * __expf(m - M) + so * __expf(mo - M);
        m = M;
    }
    __shared__ float2 wsum[4];
    const int wv = tid >> 6, lane = tid & 63;
    if (lane == 0) wsum[wv] = make_float2(m, s);
    __syncthreads();
    if (tid == 0) {
        float M = wsum[0].x, S = wsum[0].y;
        #pragma unroll
        for (int i = 1; i < 4; ++i) {
            const float M2 = fmaxf(M, wsum[i].x);
            S = S * __expf(M - M2) + wsum[i].y * __expf(wsum[i].x - M2);
            M = M2;
        }
        part[row * SMB + cb] = make_float2(M, S);
    }
}

__global__ __launch_bounds__(256) void softmax_norm(float* __restrict__ d,
                                                    const float2* __restrict__ part)
{
    const int row = blockIdx.y, cb = blockIdx.x;
    const int tid = threadIdx.x;

    // every block redundantly reduces the 25 row-partials (tiny, L2-hit)
    float M = -INFINITY, S = 0.f;
    #pragma unroll
    for (int i = 0; i < SMB; ++i) {
        const float2 ps = part[row * SMB + i];
        const float M2 = fmaxf(M, ps.x);
        S = S * __expf(M - M2) + ps.y * __expf(ps.x - M2);
        M = M2;
    }
    const float Sinv = 1.f / S;

    float* p = d + (size_t)row * N_REF + (size_t)cb * SMC;
    #pragma unroll
    for (int i = 0; i < 2; ++i) {
        const int q = tid + i * 256;
        if (q < SMC / 4) {
            float4 v = *(float4*)(p + q * 4);
            v.x = __expf(v.x - M) * Sinv;
            v.y = __expf(v.y - M) * Sinv;
            v.z = __expf(v.z - M) * Sinv;
            v.w = __expf(v.w - M) * Sinv;
            *(float4*)(p + q * 4) = v;
        }
    }
}

extern "C" void kernel_launch(void* const* d_in, const int* in_sizes, int n_in,
                              void* d_out, int out_size, void* d_ws, size_t ws_size,
                              hipStream_t stream) {
    const float* x   = (const float*)d_in[0];   // [16][32][128]
    const float* raw = (const float*)d_in[1];   // [50000][32][128]
    float* out = (float*)d_out;                 // [16][50000]
    float2* part = (float2*)d_ws;               // 16*25 float2 partials

    dist_kernel<<<N_REF / RPB, 256, 0, stream>>>(x, raw, out);
    softmax_part<<<dim3(SMB, BATCH), 256, 0, stream>>>(out, part);
    softmax_norm<<<dim3(SMB, BATCH), 256, 0, stream>>>(out, part);
}